// Round 3
// baseline (1506.402 us; speedup 1.0000x reference)
//
#include <hip/hip_runtime.h>

// ---------------------------------------------------------------------------
// AttentiveStateMLP fused forward, MI355X (gfx950)
// Lane = sample. Weights wave-uniform (scalar-cached). fp16-pair activations
// with v_dot2_f32_f16 (fp32 accumulate). x-pack and features f live in VGPR
// arrays (all indices compile-time via full unroll); only the attention ctx
// (160 words/lane) lives in LDS -> 40960 B/block -> 4 blocks/CU.
// Prep kernel folds Wqkv @ P_t per token (no nonlinearity in between).
// ---------------------------------------------------------------------------

#define B_TOTAL 131072
#define NBLK    (B_TOTAL / 64)

typedef _Float16 h2 __attribute__((ext_vector_type(2)));

__device__ __forceinline__ unsigned h2u(h2 v) { return __builtin_bit_cast(unsigned, v); }
__device__ __forceinline__ h2 u2h(unsigned u) { return __builtin_bit_cast(h2, u); }

__device__ __forceinline__ h2 pkrtz(float a, float b) {
#if __has_builtin(__builtin_amdgcn_cvt_pkrtz)
    return __builtin_bit_cast(h2, __builtin_amdgcn_cvt_pkrtz(a, b));
#else
    h2 r; r.x = (_Float16)a; r.y = (_Float16)b; return r;
#endif
}

__device__ __forceinline__ float fdot2(h2 a, h2 b, float c) {
#if __has_builtin(__builtin_amdgcn_fdot2)
    typedef __fp16 hv2 __attribute__((ext_vector_type(2)));
    return __builtin_amdgcn_fdot2(__builtin_bit_cast(hv2, a), __builtin_bit_cast(hv2, b), c, false);
#else
    return c + (float)a.x * (float)b.x + (float)a.y * (float)b.y;
#endif
}

__device__ __forceinline__ unsigned pk_rne(float a, float b) {
    h2 r; r.x = (_Float16)a; r.y = (_Float16)b;  // C cast = RNE
    return __builtin_bit_cast(unsigned, r);
}

// ---- ws layout (in 4-byte words) -----------------------------------------
#define OFF_ENC  0
#define OFF_TOK  1344
#define OFF_QKV  5952
#define OFF_WO   19776
#define OFF_WP   21824
#define OFF_TOKB 25920
#define OFF_QKVB 26240
#define N_PREP   27200

extern "C" __global__ void k_prep(
    const float* __restrict__ Wph, const float* __restrict__ Wob, const float* __restrict__ Wmi,
    const float* __restrict__ Wpr, const float* __restrict__ Wse,
    const float* __restrict__ Pph, const float* __restrict__ pbph,
    const float* __restrict__ Pob, const float* __restrict__ pbob,
    const float* __restrict__ Pmi, const float* __restrict__ pbmi,
    const float* __restrict__ Ppr, const float* __restrict__ pbpr,
    const float* __restrict__ Pse, const float* __restrict__ pbse,
    const float* __restrict__ Wqkv, const float* __restrict__ bqkv,
    const float* __restrict__ Wo, const float* __restrict__ bo,
    const float* __restrict__ Wp, unsigned* __restrict__ ws)
{
    int idx = blockIdx.x * 256 + threadIdx.x;
    if (idx >= N_PREP) return;
    float* wsf = (float*)ws;

    if (idx < OFF_TOK) {
        int rel = idx; const float* Wg; int dims, nout;
        if (rel < 960)       { Wg = Wph; dims = 29; nout = 64; }
        else if (rel < 1216) { rel -= 960;  Wg = Wob; dims = 15; nout = 32; }
        else if (rel < 1280) { rel -= 1216; Wg = Wmi; dims = 8;  nout = 16; }
        else if (rel < 1312) { rel -= 1280; Wg = Wpr; dims = 3;  nout = 16; }
        else                 { rel -= 1312; Wg = Wse; dims = 3;  nout = 16; }
        int k2 = rel / nout, u = rel % nout;
        float lo = (2*k2     < dims) ? Wg[u*dims + 2*k2]     : 0.f;
        float hi = (2*k2 + 1 < dims) ? Wg[u*dims + 2*k2 + 1] : 0.f;
        ws[OFF_ENC + idx] = pk_rne(lo, hi);
    } else if (idx < OFF_QKV) {
        int rel = idx - OFF_TOK; const float* Pg; int d;
        if (rel < 2048)      { Pg = Pph; d = 64; }
        else if (rel < 3072) { rel -= 2048; Pg = Pob; d = 32; }
        else if (rel < 3584) { rel -= 3072; Pg = Pmi; d = 16; }
        else if (rel < 4096) { rel -= 3584; Pg = Ppr; d = 16; }
        else                 { rel -= 4096; Pg = Pse; d = 16; }
        int k2 = rel / 64, u = rel % 64;
        ws[idx] = pk_rne(Pg[u*d + 2*k2], Pg[u*d + 2*k2 + 1]);
    } else if (idx < OFF_WO) {
        int rel = idx - OFF_QKV; const float* Pg; int d;
        if (rel < 6144)       { Pg = Pph; d = 64; }
        else if (rel < 9216)  { rel -= 6144;  Pg = Pob; d = 32; }
        else if (rel < 10752) { rel -= 9216;  Pg = Pmi; d = 16; }
        else if (rel < 12288) { rel -= 10752; Pg = Ppr; d = 16; }
        else                  { rel -= 12288; Pg = Pse; d = 16; }
        int kk2 = rel / 192, c = rel % 192;
        float lo = 0.f, hi = 0.f;
        for (int v = 0; v < 64; v++) {
            float wq = Wqkv[c*64 + v];
            lo += wq * Pg[v*d + 2*kk2];
            hi += wq * Pg[v*d + 2*kk2 + 1];
        }
        ws[idx] = pk_rne(lo, hi);
    } else if (idx < OFF_WP) {
        int rel = idx - OFF_WO;
        int w = rel / 64, u = rel % 64, hh = w >> 3, d2 = w & 7;
        ws[idx] = pk_rne(Wo[u*64 + 16*hh + 2*d2], Wo[u*64 + 16*hh + 2*d2 + 1]);
    } else if (idx < OFF_TOKB) {
        int rel = idx - OFF_WP;
        int u2 = rel / 128, o = rel % 128;
        ws[idx] = pk_rne(Wp[o*64 + 2*u2], Wp[o*64 + 2*u2 + 1]);
    } else if (idx < OFF_QKVB) {
        int rel = idx - OFF_TOKB;
        int t = rel / 64, u = rel % 64;
        const float* pb = (t == 0) ? pbph : (t == 1) ? pbob : (t == 2) ? pbmi : (t == 3) ? pbpr : pbse;
        wsf[idx] = pb[u] + bo[u];
    } else {
        int rel = idx - OFF_QKVB;
        int t = rel / 192, c = rel % 192;
        const float* pb = (t == 0) ? pbph : (t == 1) ? pbob : (t == 2) ? pbmi : (t == 3) ? pbpr : pbse;
        float s = bqkv[c];
        for (int v = 0; v < 64; v++) s += Wqkv[c*64 + v] * pb[v];
        wsf[idx] = s;
    }
}

// ---------------------------------------------------------------------------

template<int NOUT, int NK2>
__device__ __forceinline__ void encode(const unsigned* __restrict__ W, int wofs,
                                       const float* __restrict__ bias,
                                       const unsigned* xp, int xw0,
                                       unsigned* f, int fw0)
{
    float acc[NOUT];
#pragma unroll
    for (int u = 0; u < NOUT; u++) acc[u] = bias[u];
#pragma unroll
    for (int k2 = 0; k2 < NK2; k2++) {
        h2 a = u2h(xp[xw0 + k2]);
        const unsigned* wr = W + wofs + k2 * NOUT;
#pragma unroll
        for (int u = 0; u < NOUT; u++) acc[u] = fdot2(a, u2h(wr[u]), acc[u]);
    }
#pragma unroll
    for (int u2 = 0; u2 < NOUT / 2; u2++)
        f[fw0 + u2] = h2u(pkrtz(fmaxf(acc[2*u2], 0.f), fmaxf(acc[2*u2+1], 0.f)));
}

template<int T, int D2C, int FO2, int TOF>
__device__ __forceinline__ void token_step(const unsigned* __restrict__ W,
    const float* __restrict__ tokb, const unsigned* f,
    const unsigned* lds_ctx, int lane,
    const float* __restrict__ gamma, const float* __restrict__ beta,
    float* pooled)
{
    float a[64];
    const float* tb = tokb + T * 64;
#pragma unroll
    for (int u = 0; u < 64; u++) a[u] = tb[u];
    const unsigned* wt = W + OFF_TOK + TOF;
#pragma unroll
    for (int k2 = 0; k2 < D2C; k2++) {
        h2 f2 = u2h(f[FO2 + k2]);
        const unsigned* wr = wt + k2 * 64;
#pragma unroll
        for (int u = 0; u < 64; u++) a[u] = fdot2(f2, u2h(wr[u]), a[u]);
    }
    const unsigned* wo = W + OFF_WO;
#pragma unroll
    for (int w = 0; w < 32; w++) {
        h2 c2 = u2h(lds_ctx[(T*32 + w) * 64 + lane]);
        const unsigned* wr = wo + w * 64;
#pragma unroll
        for (int u = 0; u < 64; u++) a[u] = fdot2(c2, u2h(wr[u]), a[u]);
    }
    float mu = 0.f;
#pragma unroll
    for (int u = 0; u < 64; u++) mu += a[u];
    mu *= 0.015625f;
    float var = 0.f;
#pragma unroll
    for (int u = 0; u < 64; u++) { float d = a[u] - mu; var += d * d; }
    var *= 0.015625f;
    float rs = rsqrtf(var + 1e-5f);
#pragma unroll
    for (int u = 0; u < 64; u++) pooled[u] += (a[u] - mu) * rs * gamma[u] + beta[u];
}

extern "C" __global__ void __launch_bounds__(64, 1) k_main(
    const float* __restrict__ x,
    const float* __restrict__ b_phys, const float* __restrict__ b_obj,
    const float* __restrict__ b_mine, const float* __restrict__ b_prog,
    const float* __restrict__ b_seq,
    const float* __restrict__ gamma, const float* __restrict__ beta,
    const float* __restrict__ bp,
    const unsigned* __restrict__ W, float* __restrict__ out)
{
    __shared__ unsigned lds_ctx[160 * 64];   // ctx fp16 pairs [word][lane], 40 KiB

    const int lane = threadIdx.x;
    const int s = blockIdx.x * 64 + lane;
    const float* wsf = reinterpret_cast<const float*>(W);
    const float* tokb = wsf + OFF_TOKB;
    const float* qkvb = wsf + OFF_QKVB;

    // ---- load x row, pack per-group fp16 pairs into VGPR array ------------
    unsigned xp[31];
    {
        float xv[58];
        const float2* xp2 = reinterpret_cast<const float2*>(x + (size_t)s * 58);
#pragma unroll
        for (int i = 0; i < 29; i++) { float2 v = xp2[i]; xv[2*i] = v.x; xv[2*i+1] = v.y; }
#pragma unroll
        for (int k2 = 0; k2 < 14; k2++) xp[k2] = h2u(pkrtz(xv[2*k2], xv[2*k2+1]));
        xp[14] = h2u(pkrtz(xv[28], 0.f));
#pragma unroll
        for (int k2 = 0; k2 < 7; k2++) xp[15+k2] = h2u(pkrtz(xv[29+2*k2], xv[30+2*k2]));
        xp[22] = h2u(pkrtz(xv[43], 0.f));
#pragma unroll
        for (int k2 = 0; k2 < 4; k2++) xp[23+k2] = h2u(pkrtz(xv[44+2*k2], xv[45+2*k2]));
        xp[27] = h2u(pkrtz(xv[52], xv[53]));
        xp[28] = h2u(pkrtz(xv[54], 0.f));
        xp[29] = h2u(pkrtz(xv[55], xv[56]));
        xp[30] = h2u(pkrtz(xv[57], 0.f));
    }

    // ---- encoders: f = relu(enc(x)), f in VGPRs ---------------------------
    unsigned f[72];
    encode<64, 15>(W, OFF_ENC + 0,    b_phys, xp, 0,  f, 0);
    encode<32, 8 >(W, OFF_ENC + 960,  b_obj,  xp, 15, f, 32);
    encode<16, 4 >(W, OFF_ENC + 1216, b_mine, xp, 23, f, 48);
    encode<16, 2 >(W, OFF_ENC + 1280, b_prog, xp, 27, f, 56);
    encode<16, 2 >(W, OFF_ENC + 1312, b_seq,  xp, 29, f, 64);

    // ---- attention heads: q,k,v from folded QKV, ctx -> LDS ---------------
#pragma unroll 1
    for (int h = 0; h < 4; h++) {
        unsigned qpk[5][8], kpk[5][8], vpk[5][8];
#pragma unroll
        for (int j = 0; j < 5; j++) {
            constexpr int D2C[5]  = {32, 16, 8, 8, 8};
            constexpr int FO2[5]  = {0, 32, 48, 56, 64};
            constexpr int QOFF[5] = {0, 6144, 9216, 10752, 12288};
            float a[48];
            const float* qb = qkvb + j * 192;
#pragma unroll
            for (int d = 0; d < 16; d++) {
                a[d]      = qb[16*h + d];
                a[16 + d] = qb[64 + 16*h + d];
                a[32 + d] = qb[128 + 16*h + d];
            }
            const unsigned* wbase = W + OFF_QKV + QOFF[j];
#pragma unroll
            for (int k2 = 0; k2 < D2C[j]; k2++) {
                h2 f2 = u2h(f[FO2[j] + k2]);
                const unsigned* wr = wbase + k2 * 192 + 16 * h;
#pragma unroll
                for (int d = 0; d < 16; d++) {
                    a[d]      = fdot2(f2, u2h(wr[d]),       a[d]);
                    a[16 + d] = fdot2(f2, u2h(wr[64 + d]),  a[16 + d]);
                    a[32 + d] = fdot2(f2, u2h(wr[128 + d]), a[32 + d]);
                }
            }
#pragma unroll
            for (int d2 = 0; d2 < 8; d2++) {
                qpk[j][d2] = h2u(pkrtz(a[2*d2],      a[2*d2 + 1]));
                kpk[j][d2] = h2u(pkrtz(a[16 + 2*d2], a[17 + 2*d2]));
                vpk[j][d2] = h2u(pkrtz(a[32 + 2*d2], a[33 + 2*d2]));
            }
        }
        // scores + softmax
        float p[5][5];
#pragma unroll
        for (int i = 0; i < 5; i++) {
            float sc[5];
#pragma unroll
            for (int j = 0; j < 5; j++) {
                float sv = 0.f;
#pragma unroll
                for (int d2 = 0; d2 < 8; d2++) sv = fdot2(u2h(qpk[i][d2]), u2h(kpk[j][d2]), sv);
                sc[j] = sv * 0.25f;
            }
            float m = sc[0];
#pragma unroll
            for (int j = 1; j < 5; j++) m = fmaxf(m, sc[j]);
            float l = 0.f;
#pragma unroll
            for (int j = 0; j < 5; j++) { sc[j] = __expf(sc[j] - m); l += sc[j]; }
            float r = 1.f / l;
#pragma unroll
            for (int j = 0; j < 5; j++) p[i][j] = sc[j] * r;
        }
        // ctx = p @ v
        float ctx[5][16];
#pragma unroll
        for (int i = 0; i < 5; i++)
#pragma unroll
            for (int d = 0; d < 16; d++) ctx[i][d] = 0.f;
#pragma unroll
        for (int j = 0; j < 5; j++) {
            float vf[16];
#pragma unroll
            for (int d2 = 0; d2 < 8; d2++) { h2 t = u2h(vpk[j][d2]); vf[2*d2] = (float)t.x; vf[2*d2+1] = (float)t.y; }
#pragma unroll
            for (int i = 0; i < 5; i++) {
                float pij = p[i][j];
#pragma unroll
                for (int d = 0; d < 16; d++) ctx[i][d] += pij * vf[d];
            }
        }
        // stash ctx packed: word index t*32 + h*8 + d2  (0..159)
#pragma unroll
        for (int t = 0; t < 5; t++)
#pragma unroll
            for (int d2 = 0; d2 < 8; d2++)
                lds_ctx[(t*32 + h*8 + d2) * 64 + lane] = h2u(pkrtz(ctx[t][2*d2], ctx[t][2*d2 + 1]));
    }

    // ---- per token: h = token + ctx@Wo^T (+folded biases); LN; pool -------
    float pooled[64];
#pragma unroll
    for (int u = 0; u < 64; u++) pooled[u] = 0.f;

    token_step<0, 32, 0,  0>(W, tokb, f, lds_ctx, lane, gamma, beta, pooled);
    token_step<1, 16, 32, 2048>(W, tokb, f, lds_ctx, lane, gamma, beta, pooled);
    token_step<2, 8,  48, 3072>(W, tokb, f, lds_ctx, lane, gamma, beta, pooled);
    token_step<3, 8,  56, 3584>(W, tokb, f, lds_ctx, lane, gamma, beta, pooled);
    token_step<4, 8,  64, 4096>(W, tokb, f, lds_ctx, lane, gamma, beta, pooled);

#pragma unroll
    for (int u = 0; u < 64; u++) pooled[u] *= 0.2f;

    // ---- final projection: out = relu(pooled @ Wp^T + bp) -----------------
    float o0[64], o1[64];
#pragma unroll
    for (int o = 0; o < 64; o++) { o0[o] = bp[o]; o1[o] = bp[64 + o]; }
    const unsigned* wp = W + OFF_WP;
#pragma unroll
    for (int u2 = 0; u2 < 32; u2++) {
        h2 pw = pkrtz(pooled[2*u2], pooled[2*u2 + 1]);
        const unsigned* wr = wp + u2 * 128;
#pragma unroll
        for (int o = 0; o < 64; o++) {
            o0[o] = fdot2(pw, u2h(wr[o]),      o0[o]);
            o1[o] = fdot2(pw, u2h(wr[64 + o]), o1[o]);
        }
    }
    float4* op = reinterpret_cast<float4*>(out + (size_t)s * 128);
#pragma unroll
    for (int q = 0; q < 16; q++)
        op[q] = make_float4(fmaxf(o0[4*q], 0.f), fmaxf(o0[4*q+1], 0.f),
                            fmaxf(o0[4*q+2], 0.f), fmaxf(o0[4*q+3], 0.f));
#pragma unroll
    for (int q = 0; q < 16; q++)
        op[16 + q] = make_float4(fmaxf(o1[4*q], 0.f), fmaxf(o1[4*q+1], 0.f),
                                 fmaxf(o1[4*q+2], 0.f), fmaxf(o1[4*q+3], 0.f));
}

// ---------------------------------------------------------------------------

extern "C" void kernel_launch(void* const* d_in, const int* in_sizes, int n_in,
                              void* d_out, int out_size, void* d_ws, size_t ws_size,
                              hipStream_t stream)
{
    const float* x      = (const float*)d_in[0];
    const float* W_phys = (const float*)d_in[1];
    const float* b_phys = (const float*)d_in[2];
    const float* W_obj  = (const float*)d_in[3];
    const float* b_obj  = (const float*)d_in[4];
    const float* W_mine = (const float*)d_in[5];
    const float* b_mine = (const float*)d_in[6];
    const float* W_prog = (const float*)d_in[7];
    const float* b_prog = (const float*)d_in[8];
    const float* W_seq  = (const float*)d_in[9];
    const float* b_seq  = (const float*)d_in[10];
    const float* P_phys = (const float*)d_in[11];
    const float* pb_phys= (const float*)d_in[12];
    const float* P_obj  = (const float*)d_in[13];
    const float* pb_obj = (const float*)d_in[14];
    const float* P_mine = (const float*)d_in[15];
    const float* pb_mine= (const float*)d_in[16];
    const float* P_prog = (const float*)d_in[17];
    const float* pb_prog= (const float*)d_in[18];
    const float* P_seq  = (const float*)d_in[19];
    const float* pb_seq = (const float*)d_in[20];
    const float* Wqkv   = (const float*)d_in[21];
    const float* bqkv   = (const float*)d_in[22];
    const float* Wo     = (const float*)d_in[23];
    const float* bo     = (const float*)d_in[24];
    const float* gamma  = (const float*)d_in[25];
    const float* beta   = (const float*)d_in[26];
    const float* Wp     = (const float*)d_in[27];
    const float* bp     = (const float*)d_in[28];

    unsigned* ws = (unsigned*)d_ws;

    k_prep<<<(N_PREP + 255) / 256, 256, 0, stream>>>(
        W_phys, W_obj, W_mine, W_prog, W_seq,
        P_phys, pb_phys, P_obj, pb_obj, P_mine, pb_mine, P_prog, pb_prog, P_seq, pb_seq,
        Wqkv, bqkv, Wo, bo, Wp, ws);

    k_main<<<NBLK, 64, 0, stream>>>(
        x, b_phys, b_obj, b_mine, b_prog, b_seq,
        gamma, beta, bp, ws, (float*)d_out);
}

// Round 4
// 638.336 us; speedup vs baseline: 2.3599x; 2.3599x over previous
//
#include <hip/hip_runtime.h>

// ---------------------------------------------------------------------------
// AttentiveStateMLP fused forward, MI355X (gfx950)
// Lane = sample. Weights wave-uniform (scalar-cached s_load). fp16-pair
// activations with v_dot2_f32_f16 (fp32 accumulate). No LDS: attention ctx
// round-trips through global ws in [word][sample] coalesced layout.
// Attention restructured (k-all -> q/scores per row -> v on-the-fly) to keep
// peak live registers < 256 (no spills). Fallback LDS kernel if ws is small.
// ---------------------------------------------------------------------------

#define B_TOTAL 131072
#define NBLK    (B_TOTAL / 64)

typedef _Float16 h2 __attribute__((ext_vector_type(2)));

__device__ __forceinline__ unsigned h2u(h2 v) { return __builtin_bit_cast(unsigned, v); }
__device__ __forceinline__ h2 u2h(unsigned u) { return __builtin_bit_cast(h2, u); }

__device__ __forceinline__ h2 pkrtz(float a, float b) {
#if __has_builtin(__builtin_amdgcn_cvt_pkrtz)
    return __builtin_bit_cast(h2, __builtin_amdgcn_cvt_pkrtz(a, b));
#else
    h2 r; r.x = (_Float16)a; r.y = (_Float16)b; return r;
#endif
}

__device__ __forceinline__ float fdot2(h2 a, h2 b, float c) {
#if __has_builtin(__builtin_amdgcn_fdot2)
    typedef __fp16 hv2 __attribute__((ext_vector_type(2)));
    return __builtin_amdgcn_fdot2(__builtin_bit_cast(hv2, a), __builtin_bit_cast(hv2, b), c, false);
#else
    return c + (float)a.x * (float)b.x + (float)a.y * (float)b.y;
#endif
}

__device__ __forceinline__ unsigned pk_rne(float a, float b) {
    h2 r; r.x = (_Float16)a; r.y = (_Float16)b;  // C cast = RNE
    return __builtin_bit_cast(unsigned, r);
}

// ---- ws layout (in 4-byte words) -----------------------------------------
#define OFF_ENC  0
#define OFF_TOK  1344
#define OFF_QKV  5952
#define OFF_WO   19776
#define OFF_WP   21824
#define OFF_TOKB 25920
#define OFF_QKVB 26240
#define N_PREP   27200
#define OFF_CTX  27200              // + 160 * B_TOTAL words
#define WS_NEED  ((size_t)(N_PREP + 160 * (size_t)B_TOTAL) * 4)

extern "C" __global__ void k_prep(
    const float* __restrict__ Wph, const float* __restrict__ Wob, const float* __restrict__ Wmi,
    const float* __restrict__ Wpr, const float* __restrict__ Wse,
    const float* __restrict__ Pph, const float* __restrict__ pbph,
    const float* __restrict__ Pob, const float* __restrict__ pbob,
    const float* __restrict__ Pmi, const float* __restrict__ pbmi,
    const float* __restrict__ Ppr, const float* __restrict__ pbpr,
    const float* __restrict__ Pse, const float* __restrict__ pbse,
    const float* __restrict__ Wqkv, const float* __restrict__ bqkv,
    const float* __restrict__ Wo, const float* __restrict__ bo,
    const float* __restrict__ Wp, unsigned* __restrict__ ws)
{
    int idx = blockIdx.x * 256 + threadIdx.x;
    if (idx >= N_PREP) return;
    float* wsf = (float*)ws;

    if (idx < OFF_TOK) {
        int rel = idx; const float* Wg; int dims, nout;
        if (rel < 960)       { Wg = Wph; dims = 29; nout = 64; }
        else if (rel < 1216) { rel -= 960;  Wg = Wob; dims = 15; nout = 32; }
        else if (rel < 1280) { rel -= 1216; Wg = Wmi; dims = 8;  nout = 16; }
        else if (rel < 1312) { rel -= 1280; Wg = Wpr; dims = 3;  nout = 16; }
        else                 { rel -= 1312; Wg = Wse; dims = 3;  nout = 16; }
        int k2 = rel / nout, u = rel % nout;
        float lo = (2*k2     < dims) ? Wg[u*dims + 2*k2]     : 0.f;
        float hi = (2*k2 + 1 < dims) ? Wg[u*dims + 2*k2 + 1] : 0.f;
        ws[OFF_ENC + idx] = pk_rne(lo, hi);
    } else if (idx < OFF_QKV) {
        int rel = idx - OFF_TOK; const float* Pg; int d;
        if (rel < 2048)      { Pg = Pph; d = 64; }
        else if (rel < 3072) { rel -= 2048; Pg = Pob; d = 32; }
        else if (rel < 3584) { rel -= 3072; Pg = Pmi; d = 16; }
        else if (rel < 4096) { rel -= 3584; Pg = Ppr; d = 16; }
        else                 { rel -= 4096; Pg = Pse; d = 16; }
        int k2 = rel / 64, u = rel % 64;
        ws[idx] = pk_rne(Pg[u*d + 2*k2], Pg[u*d + 2*k2 + 1]);
    } else if (idx < OFF_WO) {
        int rel = idx - OFF_QKV; const float* Pg; int d;
        if (rel < 6144)       { Pg = Pph; d = 64; }
        else if (rel < 9216)  { rel -= 6144;  Pg = Pob; d = 32; }
        else if (rel < 10752) { rel -= 9216;  Pg = Pmi; d = 16; }
        else if (rel < 12288) { rel -= 10752; Pg = Ppr; d = 16; }
        else                  { rel -= 12288; Pg = Pse; d = 16; }
        int kk2 = rel / 192, c = rel % 192;
        float lo = 0.f, hi = 0.f;
        for (int v = 0; v < 64; v++) {
            float wq = Wqkv[c*64 + v];
            lo += wq * Pg[v*d + 2*kk2];
            hi += wq * Pg[v*d + 2*kk2 + 1];
        }
        ws[idx] = pk_rne(lo, hi);
    } else if (idx < OFF_WP) {
        int rel = idx - OFF_QKV;
        rel = idx - OFF_WO;
        int w = rel / 64, u = rel % 64, hh = w >> 3, d2 = w & 7;
        ws[idx] = pk_rne(Wo[u*64 + 16*hh + 2*d2], Wo[u*64 + 16*hh + 2*d2 + 1]);
    } else if (idx < OFF_TOKB) {
        int rel = idx - OFF_WP;
        int u2 = rel / 128, o = rel % 128;
        ws[idx] = pk_rne(Wp[o*64 + 2*u2], Wp[o*64 + 2*u2 + 1]);
    } else if (idx < OFF_QKVB) {
        int rel = idx - OFF_TOKB;
        int t = rel / 64, u = rel % 64;
        const float* pb = (t == 0) ? pbph : (t == 1) ? pbob : (t == 2) ? pbmi : (t == 3) ? pbpr : pbse;
        wsf[idx] = pb[u] + bo[u];
    } else {
        int rel = idx - OFF_QKVB;
        int t = rel / 192, c = rel % 192;
        const float* pb = (t == 0) ? pbph : (t == 1) ? pbob : (t == 2) ? pbmi : (t == 3) ? pbpr : pbse;
        float s = bqkv[c];
        for (int v = 0; v < 64; v++) s += Wqkv[c*64 + v] * pb[v];
        wsf[idx] = s;
    }
}

// ---------------------------------------------------------------------------
// shared helpers

template<int NOUT, int NK2>
__device__ __forceinline__ void encode(const unsigned* __restrict__ W, int wofs,
                                       const float* __restrict__ bias,
                                       const unsigned* xp, int xw0,
                                       unsigned* f, int fw0)
{
    float acc[NOUT];
#pragma unroll
    for (int u = 0; u < NOUT; u++) acc[u] = bias[u];
#pragma unroll
    for (int k2 = 0; k2 < NK2; k2++) {
        h2 a = u2h(xp[xw0 + k2]);
        const unsigned* wr = W + wofs + k2 * NOUT;
#pragma unroll
        for (int u = 0; u < NOUT; u++) acc[u] = fdot2(a, u2h(wr[u]), acc[u]);
    }
#pragma unroll
    for (int u2 = 0; u2 < NOUT / 2; u2++)
        f[fw0 + u2] = h2u(pkrtz(fmaxf(acc[2*u2], 0.f), fmaxf(acc[2*u2+1], 0.f)));
}

__device__ __forceinline__ void load_pack_x(const float* __restrict__ x, int s, unsigned* xp)
{
    float xv[58];
    const float2* xp2 = reinterpret_cast<const float2*>(x + (size_t)s * 58);
#pragma unroll
    for (int i = 0; i < 29; i++) { float2 v = xp2[i]; xv[2*i] = v.x; xv[2*i+1] = v.y; }
#pragma unroll
    for (int k2 = 0; k2 < 14; k2++) xp[k2] = h2u(pkrtz(xv[2*k2], xv[2*k2+1]));
    xp[14] = h2u(pkrtz(xv[28], 0.f));
#pragma unroll
    for (int k2 = 0; k2 < 7; k2++) xp[15+k2] = h2u(pkrtz(xv[29+2*k2], xv[30+2*k2]));
    xp[22] = h2u(pkrtz(xv[43], 0.f));
#pragma unroll
    for (int k2 = 0; k2 < 4; k2++) xp[23+k2] = h2u(pkrtz(xv[44+2*k2], xv[45+2*k2]));
    xp[27] = h2u(pkrtz(xv[52], xv[53]));
    xp[28] = h2u(pkrtz(xv[54], 0.f));
    xp[29] = h2u(pkrtz(xv[55], xv[56]));
    xp[30] = h2u(pkrtz(xv[57], 0.f));
}

// ---------------------------------------------------------------------------
// Primary kernel: ctx via global ws, zero LDS.

constexpr int cD2C[5]  = {32, 16, 8, 8, 8};
constexpr int cFO2[5]  = {0, 32, 48, 56, 64};
constexpr int cQOFF[5] = {0, 6144, 9216, 10752, 12288};
constexpr int cTOF[5]  = {0, 2048, 3072, 3584, 4096};

extern "C" __global__ void __launch_bounds__(64, 2) k_main_g(
    const float* __restrict__ x,
    const float* __restrict__ b_phys, const float* __restrict__ b_obj,
    const float* __restrict__ b_mine, const float* __restrict__ b_prog,
    const float* __restrict__ b_seq,
    const float* __restrict__ gamma, const float* __restrict__ beta,
    const float* __restrict__ bp,
    const unsigned* __restrict__ W, unsigned* ctxg, float* __restrict__ out)
{
    const int lane = threadIdx.x;
    const int s = blockIdx.x * 64 + lane;
    const float* wsf = reinterpret_cast<const float*>(W);
    const float* tokb = wsf + OFF_TOKB;
    const float* qkvb = wsf + OFF_QKVB;

    // ---- phase 1: x -> f (VGPR, fp16 pairs) -------------------------------
    unsigned f[72];
    {
        unsigned xp[31];
        load_pack_x(x, s, xp);
        encode<64, 15>(W, OFF_ENC + 0,    b_phys, xp, 0,  f, 0);
        encode<32, 8 >(W, OFF_ENC + 960,  b_obj,  xp, 15, f, 32);
        encode<16, 4 >(W, OFF_ENC + 1216, b_mine, xp, 23, f, 48);
        encode<16, 2 >(W, OFF_ENC + 1280, b_prog, xp, 27, f, 56);
        encode<16, 2 >(W, OFF_ENC + 1312, b_seq,  xp, 29, f, 64);
    }

    // ---- phase 2: attention, ctx -> global ws -----------------------------
#pragma unroll 1
    for (int h = 0; h < 4; h++) {
        // k for all tokens (packed)
        unsigned kpk[40];
#pragma unroll
        for (int t = 0; t < 5; t++) {
            float a[16];
            const float* qb = qkvb + t * 192 + 64 + 16 * h;
#pragma unroll
            for (int d = 0; d < 16; d++) a[d] = qb[d];
            const unsigned* wbase = W + OFF_QKV + cQOFF[t] + 64 + 16 * h;
#pragma unroll
            for (int k2 = 0; k2 < cD2C[t]; k2++) {
                h2 f2 = u2h(f[cFO2[t] + k2]);
                const unsigned* wr = wbase + k2 * 192;
#pragma unroll
                for (int d = 0; d < 16; d++) a[d] = fdot2(f2, u2h(wr[d]), a[d]);
            }
#pragma unroll
            for (int d2 = 0; d2 < 8; d2++) kpk[t*8 + d2] = h2u(pkrtz(a[2*d2], a[2*d2+1]));
        }
        // q per row -> scores -> softmax
        float p[5][5];
#pragma unroll
        for (int i = 0; i < 5; i++) {
            float a[16];
            const float* qb = qkvb + i * 192 + 16 * h;
#pragma unroll
            for (int d = 0; d < 16; d++) a[d] = qb[d];
            const unsigned* wbase = W + OFF_QKV + cQOFF[i] + 16 * h;
#pragma unroll
            for (int k2 = 0; k2 < cD2C[i]; k2++) {
                h2 f2 = u2h(f[cFO2[i] + k2]);
                const unsigned* wr = wbase + k2 * 192;
#pragma unroll
                for (int d = 0; d < 16; d++) a[d] = fdot2(f2, u2h(wr[d]), a[d]);
            }
            unsigned qpk[8];
#pragma unroll
            for (int d2 = 0; d2 < 8; d2++) qpk[d2] = h2u(pkrtz(a[2*d2], a[2*d2+1]));
            float sc[5];
#pragma unroll
            for (int j = 0; j < 5; j++) {
                float sv = 0.f;
#pragma unroll
                for (int d2 = 0; d2 < 8; d2++) sv = fdot2(u2h(qpk[d2]), u2h(kpk[j*8 + d2]), sv);
                sc[j] = sv * 0.25f;
            }
            float m = sc[0];
#pragma unroll
            for (int j = 1; j < 5; j++) m = fmaxf(m, sc[j]);
            float l = 0.f;
#pragma unroll
            for (int j = 0; j < 5; j++) { sc[j] = __expf(sc[j] - m); l += sc[j]; }
            float r = 1.f / l;
#pragma unroll
            for (int j = 0; j < 5; j++) p[i][j] = sc[j] * r;
        }
        // v per token on the fly; ctx accumulate fp32; store packed
        float cacc[5][16];
#pragma unroll
        for (int i = 0; i < 5; i++)
#pragma unroll
            for (int d = 0; d < 16; d++) cacc[i][d] = 0.f;
#pragma unroll
        for (int j = 0; j < 5; j++) {
            float a[16];
            const float* qb = qkvb + j * 192 + 128 + 16 * h;
#pragma unroll
            for (int d = 0; d < 16; d++) a[d] = qb[d];
            const unsigned* wbase = W + OFF_QKV + cQOFF[j] + 128 + 16 * h;
#pragma unroll
            for (int k2 = 0; k2 < cD2C[j]; k2++) {
                h2 f2 = u2h(f[cFO2[j] + k2]);
                const unsigned* wr = wbase + k2 * 192;
#pragma unroll
                for (int d = 0; d < 16; d++) a[d] = fdot2(f2, u2h(wr[d]), a[d]);
            }
#pragma unroll
            for (int i = 0; i < 5; i++) {
                float pij = p[i][j];
#pragma unroll
                for (int d = 0; d < 16; d++) cacc[i][d] += pij * a[d];
            }
        }
#pragma unroll
        for (int i = 0; i < 5; i++)
#pragma unroll
            for (int d2 = 0; d2 < 8; d2++)
                ctxg[OFF_CTX + (size_t)(h*40 + i*8 + d2) * B_TOTAL + s] =
                    h2u(pkrtz(cacc[i][2*d2], cacc[i][2*d2+1]));
    }

    // ---- phase 3: per token h = tok + ctx@Wo^T; LN; pool ------------------
    float pooled[64];
#pragma unroll
    for (int u = 0; u < 64; u++) pooled[u] = 0.f;

#pragma unroll 1
    for (int t = 0; t < 5; t++) {
        float a[64];
        const float* tb = tokb + t * 64;
#pragma unroll
        for (int u = 0; u < 64; u++) a[u] = tb[u];
        const unsigned* wt = W + OFF_TOK + cTOF[t];
#pragma unroll
        for (int k2 = 0; k2 < 32; k2++) {
            if (k2 < cD2C[t]) {
                h2 f2 = u2h(f[cFO2[t] + k2]);
                const unsigned* wr = wt + k2 * 64;
#pragma unroll
                for (int u = 0; u < 64; u++) a[u] = fdot2(f2, u2h(wr[u]), a[u]);
            }
        }
#pragma unroll
        for (int h4 = 0; h4 < 4; h4++) {
            unsigned cpk[8];
#pragma unroll
            for (int d2 = 0; d2 < 8; d2++)
                cpk[d2] = ctxg[OFF_CTX + (size_t)(h4*40 + t*8 + d2) * B_TOTAL + s];
            const unsigned* wo = W + OFF_WO + (h4*8) * 64;
#pragma unroll
            for (int w = 0; w < 8; w++) {
                h2 c2 = u2h(cpk[w]);
                const unsigned* wr = wo + w * 64;
#pragma unroll
                for (int u = 0; u < 64; u++) a[u] = fdot2(c2, u2h(wr[u]), a[u]);
            }
        }
        float mu = 0.f;
#pragma unroll
        for (int u = 0; u < 64; u++) mu += a[u];
        mu *= 0.015625f;
        float var = 0.f;
#pragma unroll
        for (int u = 0; u < 64; u++) { float d = a[u] - mu; var += d * d; }
        var *= 0.015625f;
        float rs = rsqrtf(var + 1e-5f);
#pragma unroll
        for (int u = 0; u < 64; u++) pooled[u] += (a[u] - mu) * rs * gamma[u] + beta[u];
    }

    // ---- phase 4: out = relu((pooled/5) @ Wp^T + bp) ----------------------
    unsigned ppk[32];
#pragma unroll
    for (int u2 = 0; u2 < 32; u2++)
        ppk[u2] = h2u(pkrtz(pooled[2*u2] * 0.2f, pooled[2*u2+1] * 0.2f));

    float o0[64], o1[64];
#pragma unroll
    for (int o = 0; o < 64; o++) { o0[o] = bp[o]; o1[o] = bp[64 + o]; }
    const unsigned* wp = W + OFF_WP;
#pragma unroll
    for (int u2 = 0; u2 < 32; u2++) {
        h2 pw = u2h(ppk[u2]);
        const unsigned* wr = wp + u2 * 128;
#pragma unroll
        for (int o = 0; o < 64; o++) {
            o0[o] = fdot2(pw, u2h(wr[o]),      o0[o]);
            o1[o] = fdot2(pw, u2h(wr[64 + o]), o1[o]);
        }
    }
    float4* op = reinterpret_cast<float4*>(out + (size_t)s * 128);
#pragma unroll
    for (int q = 0; q < 16; q++)
        op[q] = make_float4(fmaxf(o0[4*q], 0.f), fmaxf(o0[4*q+1], 0.f),
                            fmaxf(o0[4*q+2], 0.f), fmaxf(o0[4*q+3], 0.f));
#pragma unroll
    for (int q = 0; q < 16; q++)
        op[16 + q] = make_float4(fmaxf(o1[4*q], 0.f), fmaxf(o1[4*q+1], 0.f),
                                 fmaxf(o1[4*q+2], 0.f), fmaxf(o1[4*q+3], 0.f));
}

// ---------------------------------------------------------------------------
// Fallback kernel (round-3 structure, LDS ctx) — used only if ws too small.

template<int T, int D2C, int FO2, int TOF>
__device__ __forceinline__ void token_step_l(const unsigned* __restrict__ W,
    const float* __restrict__ tokb, const unsigned* f,
    const unsigned* lds_ctx, int lane,
    const float* __restrict__ gamma, const float* __restrict__ beta,
    float* pooled)
{
    float a[64];
    const float* tb = tokb + T * 64;
#pragma unroll
    for (int u = 0; u < 64; u++) a[u] = tb[u];
    const unsigned* wt = W + OFF_TOK + TOF;
#pragma unroll
    for (int k2 = 0; k2 < D2C; k2++) {
        h2 f2 = u2h(f[FO2 + k2]);
        const unsigned* wr = wt + k2 * 64;
#pragma unroll
        for (int u = 0; u < 64; u++) a[u] = fdot2(f2, u2h(wr[u]), a[u]);
    }
    const unsigned* wo = W + OFF_WO;
#pragma unroll
    for (int w = 0; w < 32; w++) {
        h2 c2 = u2h(lds_ctx[(T*32 + w) * 64 + lane]);
        const unsigned* wr = wo + w * 64;
#pragma unroll
        for (int u = 0; u < 64; u++) a[u] = fdot2(c2, u2h(wr[u]), a[u]);
    }
    float mu = 0.f;
#pragma unroll
    for (int u = 0; u < 64; u++) mu += a[u];
    mu *= 0.015625f;
    float var = 0.f;
#pragma unroll
    for (int u = 0; u < 64; u++) { float d = a[u] - mu; var += d * d; }
    var *= 0.015625f;
    float rs = rsqrtf(var + 1e-5f);
#pragma unroll
    for (int u = 0; u < 64; u++) pooled[u] += (a[u] - mu) * rs * gamma[u] + beta[u];
}

extern "C" __global__ void __launch_bounds__(64, 1) k_main_l(
    const float* __restrict__ x,
    const float* __restrict__ b_phys, const float* __restrict__ b_obj,
    const float* __restrict__ b_mine, const float* __restrict__ b_prog,
    const float* __restrict__ b_seq,
    const float* __restrict__ gamma, const float* __restrict__ beta,
    const float* __restrict__ bp,
    const unsigned* __restrict__ W, float* __restrict__ out)
{
    __shared__ unsigned lds_ctx[160 * 64];

    const int lane = threadIdx.x;
    const int s = blockIdx.x * 64 + lane;
    const float* wsf = reinterpret_cast<const float*>(W);
    const float* tokb = wsf + OFF_TOKB;
    const float* qkvb = wsf + OFF_QKVB;

    unsigned xp[31];
    load_pack_x(x, s, xp);

    unsigned f[72];
    encode<64, 15>(W, OFF_ENC + 0,    b_phys, xp, 0,  f, 0);
    encode<32, 8 >(W, OFF_ENC + 960,  b_obj,  xp, 15, f, 32);
    encode<16, 4 >(W, OFF_ENC + 1216, b_mine, xp, 23, f, 48);
    encode<16, 2 >(W, OFF_ENC + 1280, b_prog, xp, 27, f, 56);
    encode<16, 2 >(W, OFF_ENC + 1312, b_seq,  xp, 29, f, 64);

#pragma unroll 1
    for (int h = 0; h < 4; h++) {
        unsigned qpk[5][8], kpk[5][8], vpk[5][8];
#pragma unroll
        for (int j = 0; j < 5; j++) {
            float a[48];
            const float* qb = qkvb + j * 192;
#pragma unroll
            for (int d = 0; d < 16; d++) {
                a[d]      = qb[16*h + d];
                a[16 + d] = qb[64 + 16*h + d];
                a[32 + d] = qb[128 + 16*h + d];
            }
            const unsigned* wbase = W + OFF_QKV + cQOFF[j];
#pragma unroll
            for (int k2 = 0; k2 < cD2C[j]; k2++) {
                h2 f2 = u2h(f[cFO2[j] + k2]);
                const unsigned* wr = wbase + k2 * 192 + 16 * h;
#pragma unroll
                for (int d = 0; d < 16; d++) {
                    a[d]      = fdot2(f2, u2h(wr[d]),       a[d]);
                    a[16 + d] = fdot2(f2, u2h(wr[64 + d]),  a[16 + d]);
                    a[32 + d] = fdot2(f2, u2h(wr[128 + d]), a[32 + d]);
                }
            }
#pragma unroll
            for (int d2 = 0; d2 < 8; d2++) {
                qpk[j][d2] = h2u(pkrtz(a[2*d2],      a[2*d2 + 1]));
                kpk[j][d2] = h2u(pkrtz(a[16 + 2*d2], a[17 + 2*d2]));
                vpk[j][d2] = h2u(pkrtz(a[32 + 2*d2], a[33 + 2*d2]));
            }
        }
        float p[5][5];
#pragma unroll
        for (int i = 0; i < 5; i++) {
            float sc[5];
#pragma unroll
            for (int j = 0; j < 5; j++) {
                float sv = 0.f;
#pragma unroll
                for (int d2 = 0; d2 < 8; d2++) sv = fdot2(u2h(qpk[i][d2]), u2h(kpk[j][d2]), sv);
                sc[j] = sv * 0.25f;
            }
            float m = sc[0];
#pragma unroll
            for (int j = 1; j < 5; j++) m = fmaxf(m, sc[j]);
            float l = 0.f;
#pragma unroll
            for (int j = 0; j < 5; j++) { sc[j] = __expf(sc[j] - m); l += sc[j]; }
            float r = 1.f / l;
#pragma unroll
            for (int j = 0; j < 5; j++) p[i][j] = sc[j] * r;
        }
        float ctx[5][16];
#pragma unroll
        for (int i = 0; i < 5; i++)
#pragma unroll
            for (int d = 0; d < 16; d++) ctx[i][d] = 0.f;
#pragma unroll
        for (int j = 0; j < 5; j++) {
            float vf[16];
#pragma unroll
            for (int d2 = 0; d2 < 8; d2++) { h2 t = u2h(vpk[j][d2]); vf[2*d2] = (float)t.x; vf[2*d2+1] = (float)t.y; }
#pragma unroll
            for (int i = 0; i < 5; i++) {
                float pij = p[i][j];
#pragma unroll
                for (int d = 0; d < 16; d++) ctx[i][d] += pij * vf[d];
            }
        }
#pragma unroll
        for (int t = 0; t < 5; t++)
#pragma unroll
            for (int d2 = 0; d2 < 8; d2++)
                lds_ctx[(t*32 + h*8 + d2) * 64 + lane] = h2u(pkrtz(ctx[t][2*d2], ctx[t][2*d2 + 1]));
    }

    float pooled[64];
#pragma unroll
    for (int u = 0; u < 64; u++) pooled[u] = 0.f;

    token_step_l<0, 32, 0,  0>(W, tokb, f, lds_ctx, lane, gamma, beta, pooled);
    token_step_l<1, 16, 32, 2048>(W, tokb, f, lds_ctx, lane, gamma, beta, pooled);
    token_step_l<2, 8,  48, 3072>(W, tokb, f, lds_ctx, lane, gamma, beta, pooled);
    token_step_l<3, 8,  56, 3584>(W, tokb, f, lds_ctx, lane, gamma, beta, pooled);
    token_step_l<4, 8,  64, 4096>(W, tokb, f, lds_ctx, lane, gamma, beta, pooled);

#pragma unroll
    for (int u = 0; u < 64; u++) pooled[u] *= 0.2f;

    float o0[64], o1[64];
#pragma unroll
    for (int o = 0; o < 64; o++) { o0[o] = bp[o]; o1[o] = bp[64 + o]; }
    const unsigned* wp = W + OFF_WP;
#pragma unroll
    for (int u2 = 0; u2 < 32; u2++) {
        h2 pw = pkrtz(pooled[2*u2], pooled[2*u2 + 1]);
        const unsigned* wr = wp + u2 * 128;
#pragma unroll
        for (int o = 0; o < 64; o++) {
            o0[o] = fdot2(pw, u2h(wr[o]),      o0[o]);
            o1[o] = fdot2(pw, u2h(wr[64 + o]), o1[o]);
        }
    }
    float4* op = reinterpret_cast<float4*>(out + (size_t)s * 128);
#pragma unroll
    for (int q = 0; q < 16; q++)
        op[q] = make_float4(fmaxf(o0[4*q], 0.f), fmaxf(o0[4*q+1], 0.f),
                            fmaxf(o0[4*q+2], 0.f), fmaxf(o0[4*q+3], 0.f));
#pragma unroll
    for (int q = 0; q < 16; q++)
        op[16 + q] = make_float4(fmaxf(o1[4*q], 0.f), fmaxf(o1[4*q+1], 0.f),
                                 fmaxf(o1[4*q+2], 0.f), fmaxf(o1[4*q+3], 0.f));
}

// ---------------------------------------------------------------------------

extern "C" void kernel_launch(void* const* d_in, const int* in_sizes, int n_in,
                              void* d_out, int out_size, void* d_ws, size_t ws_size,
                              hipStream_t stream)
{
    const float* x      = (const float*)d_in[0];
    const float* W_phys = (const float*)d_in[1];
    const float* b_phys = (const float*)d_in[2];
    const float* W_obj  = (const float*)d_in[3];
    const float* b_obj  = (const float*)d_in[4];
    const float* W_mine = (const float*)d_in[5];
    const float* b_mine = (const float*)d_in[6];
    const float* W_prog = (const float*)d_in[7];
    const float* b_prog = (const float*)d_in[8];
    const float* W_seq  = (const float*)d_in[9];
    const float* b_seq  = (const float*)d_in[10];
    const float* P_phys = (const float*)d_in[11];
    const float* pb_phys= (const float*)d_in[12];
    const float* P_obj  = (const float*)d_in[13];
    const float* pb_obj = (const float*)d_in[14];
    const float* P_mine = (const float*)d_in[15];
    const float* pb_mine= (const float*)d_in[16];
    const float* P_prog = (const float*)d_in[17];
    const float* pb_prog= (const float*)d_in[18];
    const float* P_seq  = (const float*)d_in[19];
    const float* pb_seq = (const float*)d_in[20];
    const float* Wqkv   = (const float*)d_in[21];
    const float* bqkv   = (const float*)d_in[22];
    const float* Wo     = (const float*)d_in[23];
    const float* bo     = (const float*)d_in[24];
    const float* gamma  = (const float*)d_in[25];
    const float* beta   = (const float*)d_in[26];
    const float* Wp     = (const float*)d_in[27];
    const float* bp     = (const float*)d_in[28];

    unsigned* ws = (unsigned*)d_ws;

    k_prep<<<(N_PREP + 255) / 256, 256, 0, stream>>>(
        W_phys, W_obj, W_mine, W_prog, W_seq,
        P_phys, pb_phys, P_obj, pb_obj, P_mine, pb_mine, P_prog, pb_prog, P_seq, pb_seq,
        Wqkv, bqkv, Wo, bo, Wp, ws);

    if (ws_size >= WS_NEED) {
        k_main_g<<<NBLK, 64, 0, stream>>>(
            x, b_phys, b_obj, b_mine, b_prog, b_seq,
            gamma, beta, bp, ws, ws, (float*)d_out);
    } else {
        k_main_l<<<NBLK, 64, 0, stream>>>(
            x, b_phys, b_obj, b_mine, b_prog, b_seq,
            gamma, beta, bp, ws, (float*)d_out);
    }
}